// Round 1
// baseline (35.383 us; speedup 1.0000x reference)
//
#include <hip/hip_runtime.h>

// Problem constants (from reference)
constexpr int B = 1024;
constexpr int N = 4096;
constexpr int CHUNKS = 16;          // N-chunks per batch
constexpr int BLK = 256;            // threads per block == chunk length
constexpr float C01 = 0.4082482904638630f;  // sqrt(0.5)/sqrt(3)
constexpr float C11 = 0.2886751345948129f;  // sqrt(0.5)/sqrt(6)

// Stage 1: per-(batch, chunk) partial sums of tp_out over n.
// grid = B*CHUNKS blocks of 256 threads; each thread handles one n.
__global__ __launch_bounds__(BLK) void tp_reduce_kernel(
    const float* __restrict__ feats,      // (B, N, 8)
    const float* __restrict__ edge_attr,  // (B, N, 3)
    const float* __restrict__ w_path0,    // (5,)
    const float* __restrict__ w_path1,    // (1,)
    float* __restrict__ part)             // (B*CHUNKS, 3)
{
    const int blk   = blockIdx.x;
    const int b     = blk >> 4;          // / CHUNKS
    const int chunk = blk & (CHUNKS - 1);
    const int n     = chunk * BLK + threadIdx.x;
    const long idx  = (long)b * N + n;

    // feats: 32 contiguous bytes per lane, 16B-aligned -> two float4 loads
    const float4* fp = reinterpret_cast<const float4*>(feats + idx * 8);
    float4 f0 = fp[0];
    float4 f1 = fp[1];

    const float* ep = edge_attr + idx * 3;
    float e0 = ep[0], e1 = ep[1], e2 = ep[2];

    // uniform small weights (broadcast loads, cached)
    float s = f0.x * w_path0[0] + f0.y * w_path0[1] + f0.z * w_path0[2]
            + f0.w * w_path0[3] + f1.x * w_path0[4];
    float v0 = f1.y, v1 = f1.z, v2 = f1.w;
    float c11w = C11 * w_path1[0];
    float c01s = C01 * s;

    float t0 = c01s * e0 + c11w * (v1 * e2 - v2 * e1);
    float t1 = c01s * e1 + c11w * (v2 * e0 - v0 * e2);
    float t2 = c01s * e2 + c11w * (v0 * e1 - v1 * e0);

    // block tree-reduce the 3 components
    __shared__ float r0[BLK], r1[BLK], r2[BLK];
    int t = threadIdx.x;
    r0[t] = t0; r1[t] = t1; r2[t] = t2;
    __syncthreads();
    #pragma unroll
    for (int off = BLK / 2; off > 0; off >>= 1) {
        if (t < off) {
            r0[t] += r0[t + off];
            r1[t] += r1[t + off];
            r2[t] += r2[t + off];
        }
        __syncthreads();
    }
    if (t == 0) {
        float* p = part + (long)blk * 3;
        p[0] = r0[0];
        p[1] = r1[0];
        p[2] = r2[0];
    }
}

// Stage 2: finish mean, then MLP 3 -> 128(relu) -> 3 per batch row.
// grid = B blocks of 128 threads (one per hidden unit).
__global__ __launch_bounds__(128) void mlp_kernel(
    const float* __restrict__ part,  // (B*CHUNKS, 3)
    const float* __restrict__ W1,    // (3, 128)
    const float* __restrict__ b1,    // (128,)
    const float* __restrict__ W2,    // (128, 3)
    const float* __restrict__ b2,    // (3,)
    float* __restrict__ out)         // (B, 3)
{
    const int b = blockIdx.x;
    const int j = threadIdx.x;  // 0..127

    __shared__ float g[3];
    if (j < 3) {
        float acc = 0.0f;
        const float* p = part + (long)b * CHUNKS * 3 + j;
        #pragma unroll
        for (int c = 0; c < CHUNKS; ++c) acc += p[c * 3];
        g[j] = acc * (1.0f / (float)N);
    }
    __syncthreads();

    float h = b1[j] + g[0] * W1[j] + g[1] * W1[128 + j] + g[2] * W1[256 + j];
    h = fmaxf(h, 0.0f);

    __shared__ float red[3][128];
    red[0][j] = h * W2[j * 3 + 0];
    red[1][j] = h * W2[j * 3 + 1];
    red[2][j] = h * W2[j * 3 + 2];
    __syncthreads();
    #pragma unroll
    for (int off = 64; off > 0; off >>= 1) {
        if (j < off) {
            red[0][j] += red[0][j + off];
            red[1][j] += red[1][j + off];
            red[2][j] += red[2][j + off];
        }
        __syncthreads();
    }
    if (j < 3) out[(long)b * 3 + j] = red[j][0] + b2[j];
}

extern "C" void kernel_launch(void* const* d_in, const int* in_sizes, int n_in,
                              void* d_out, int out_size, void* d_ws, size_t ws_size,
                              hipStream_t stream) {
    const float* feats     = (const float*)d_in[0];
    const float* edge_attr = (const float*)d_in[1];
    const float* w_path0   = (const float*)d_in[2];
    const float* w_path1   = (const float*)d_in[3];
    const float* W1        = (const float*)d_in[4];
    const float* b1        = (const float*)d_in[5];
    const float* W2        = (const float*)d_in[6];
    const float* b2        = (const float*)d_in[7];
    float* out = (float*)d_out;

    float* part = (float*)d_ws;  // B*CHUNKS*3 floats = 192 KiB

    tp_reduce_kernel<<<B * CHUNKS, BLK, 0, stream>>>(feats, edge_attr, w_path0,
                                                     w_path1, part);
    mlp_kernel<<<B, 128, 0, stream>>>(part, W1, b1, W2, b2, out);
}